// Round 2
// baseline (7048.537 us; speedup 1.0000x reference)
//
#include <hip/hip_runtime.h>
#include <hip/hip_bf16.h>
#include <stdint.h>

// ---------------------------------------------------------------------------
// SpMiddle dense-emulated sparse conv stack, fp32 direct conv version.
// Layout NDHWC throughout (channels innermost), matching the reference.
// ---------------------------------------------------------------------------

#define HCONST 128
#define WCONST 128

// ---- scatter: last-write-wins via owner = atomicMax(point index) ----------
__global__ void scatter_owner_kernel(const int* __restrict__ coords,
                                     int* __restrict__ owner,
                                     unsigned char* __restrict__ mask0, int N) {
    int n = blockIdx.x * blockDim.x + threadIdx.x;
    if (n >= N) return;
    int z = coords[n * 4 + 1];
    int y = coords[n * 4 + 2];
    int x = coords[n * 4 + 3];
    int pos = (z * HCONST + y) * WCONST + x;
    atomicMax(&owner[pos], n);
    mask0[pos] = 1;
}

__global__ void scatter_write_kernel(const float* __restrict__ feats,
                                     const int* __restrict__ coords,
                                     const int* __restrict__ owner,
                                     float* __restrict__ grid, int N) {
    int n = blockIdx.x * blockDim.x + threadIdx.x;
    if (n >= N) return;
    int z = coords[n * 4 + 1];
    int y = coords[n * 4 + 2];
    int x = coords[n * 4 + 3];
    int pos = (z * HCONST + y) * WCONST + x;
    if (owner[pos] != n) return;  // only the last point at this voxel writes
    const float4* s = (const float4*)(feats + (size_t)n * 16);
    float4* d = (float4*)(grid + (size_t)pos * 16);
    d[0] = s[0]; d[1] = s[1]; d[2] = s[2]; d[3] = s[3];
}

// ---- occupancy mask: OR over conv window -----------------------------------
template <int KD, int KHW, int SD, int PD, int PHW>
__global__ void occupancy_kernel(const unsigned char* __restrict__ min_,
                                 unsigned char* __restrict__ mout,
                                 int Din, int Dout) {
    int idx = blockIdx.x * blockDim.x + threadIdx.x;
    int total = Dout * HCONST * WCONST;
    if (idx >= total) return;
    int ow = idx % WCONST;
    int oh = (idx / WCONST) % HCONST;
    int od = idx / (WCONST * HCONST);
    unsigned char r = 0;
    for (int kd = 0; kd < KD; ++kd) {
        int d = od * SD - PD + kd;
        if (d < 0 || d >= Din) continue;
        for (int kh = 0; kh < KHW; ++kh) {
            int h = oh - PHW + kh;
            if ((unsigned)h >= (unsigned)HCONST) continue;
            for (int kw = 0; kw < KHW; ++kw) {
                int w = ow - PHW + kw;
                if ((unsigned)w >= (unsigned)WCONST) continue;
                r |= min_[(d * HCONST + h) * WCONST + w];
            }
        }
    }
    mout[idx] = r ? 1 : 0;
}

// ---- direct conv + BN + ReLU + mask ----------------------------------------
// Block: 256 threads covering 32 w-positions x COUT channels of one (od, oh).
// co = t % COUT, g = t / COUT; each thread owns WPT = 32/G consecutive w.
// Input row staged in LDS transposed to [ci][w] so the thread's w-window is
// contiguous (vectorizable ds_read; wave-uniform address -> broadcast).
template <int CIN, int COUT, int KD, int KHW, int SD, int PD, int PHW>
__global__ __launch_bounds__(256) void conv_bnrelu_kernel(
    const float* __restrict__ x, const float* __restrict__ wgt,
    const float* __restrict__ scale, const float* __restrict__ bias,
    const unsigned char* __restrict__ mask, float* __restrict__ out,
    int Din) {
    constexpr int G   = 256 / COUT;       // w-groups per block
    constexpr int WPT = 32 / G;           // outputs per thread along w
    constexpr int WS  = 32 + KHW - 1;     // staged w extent (34 or 32)
    constexpr int WSP = (WS + 3) & ~3;    // pad to 16B for vector ds_read
    __shared__ float lds[CIN * WSP];

    const int t  = threadIdx.x;
    const int co = t % COUT;
    const int g  = t / COUT;
    const int wbase = blockIdx.x * 32;
    const int oh = blockIdx.y;
    const int od = blockIdx.z;

    float acc[WPT];
#pragma unroll
    for (int j = 0; j < WPT; ++j) acc[j] = 0.f;

    for (int kd = 0; kd < KD; ++kd) {
        int din = od * SD - PD + kd;
        if (din < 0 || din >= Din) continue;            // block-uniform
        for (int kh = 0; kh < KHW; ++kh) {
            int hin = oh - PHW + kh;
            if (hin < 0 || hin >= HCONST) continue;     // block-uniform
            __syncthreads();                            // protect prev LDS use
            const float* src = x + ((size_t)(din * HCONST + hin) * WCONST) * CIN;
            for (int e = t; e < WS * CIN; e += 256) {
                int wo = e / CIN;
                int ci = e % CIN;
                int win = wbase + wo - PHW;
                float v = (win >= 0 && win < WCONST) ? src[(size_t)win * CIN + ci] : 0.f;
                lds[ci * WSP + wo] = v;
            }
            __syncthreads();
            const float* wrow = wgt + ((size_t)(kd * KHW + kh) * KHW) * CIN * COUT;
            for (int ci = 0; ci < CIN; ++ci) {
                float xv[WPT + KHW - 1];
#pragma unroll
                for (int u = 0; u < WPT + KHW - 1; ++u)
                    xv[u] = lds[ci * WSP + g * WPT + u];
#pragma unroll
                for (int kw = 0; kw < KHW; ++kw) {
                    float wv = wrow[((size_t)(kw * CIN + ci)) * COUT + co];
#pragma unroll
                    for (int j = 0; j < WPT; ++j)
                        acc[j] = fmaf(xv[j + kw], wv, acc[j]);
                }
            }
        }
    }

    // epilogue: y = max(acc*s + b, 0) * mask
    float s = scale[co];
    float b = bias[co];
    const unsigned char* mrow = mask + ((size_t)od * HCONST + oh) * WCONST + wbase;
    float* orow = out + (((size_t)od * HCONST + oh) * WCONST + wbase) * COUT;
#pragma unroll
    for (int j = 0; j < WPT; ++j) {
        int w = g * WPT + j;
        float y = fmaxf(acc[j] * s + b, 0.f);
        y = mrow[w] ? y : 0.f;
        orow[(size_t)w * COUT + co] = y;
    }
}

// ---------------------------------------------------------------------------
extern "C" void kernel_launch(void* const* d_in, const int* in_sizes, int n_in,
                              void* d_out, int out_size, void* d_ws, size_t ws_size,
                              hipStream_t stream) {
    const float* feats  = (const float*)d_in[0];
    const int*   coords = (const int*)d_in[1];
    const float* W_[11]; const float* S_[11]; const float* B_[11];
    for (int i = 0; i < 11; ++i) {
        W_[i] = (const float*)d_in[2 + 3 * i];   // dict order: w_i, s_i, b_i
        S_[i] = (const float*)d_in[3 + 3 * i];
        B_[i] = (const float*)d_in[4 + 3 * i];
    }
    const int N = in_sizes[0] / 16;

    // ---- workspace layout (all 256B aligned) ----
    // buf0 / buf1: ping-pong activations, 22,020,096 floats each (max layer).
    // grid (41*128*128*16 floats = 43 MB) lives at the start of buf1 — it is
    // consumed by L0 (writing buf0) and overwritten by L1's output.
    char* ws = (char*)d_ws;
    size_t off = 0;
    auto alloc = [&](size_t bytes) {
        void* p = ws + off;
        off = (off + bytes + 255) & ~(size_t)255;
        return p;
    };
    const size_t BUF_BYTES = (size_t)22020096 * 4;   // 88,080,384
    float* buf0 = (float*)alloc(BUF_BYTES);
    float* buf1 = (float*)alloc(BUF_BYTES);
    unsigned char* m0 = (unsigned char*)alloc(671744);
    unsigned char* m1 = (unsigned char*)alloc(344064);
    unsigned char* m2 = (unsigned char*)alloc(163840);
    unsigned char* m3 = (unsigned char*)alloc(65536);
    int* owner = (int*)alloc((size_t)671744 * 4);
    (void)ws_size; (void)n_in; (void)out_size;

    float* grid0 = buf1;                 // (41,128,128,16) aliased into buf1
    const size_t GRID_BYTES = (size_t)41 * 128 * 128 * 16 * 4;

    hipMemsetAsync(grid0, 0, GRID_BYTES, stream);
    hipMemsetAsync(m0, 0, 671744, stream);
    hipMemsetAsync(owner, 0xFF, (size_t)671744 * 4, stream);   // owner = -1

    scatter_owner_kernel<<<(N + 255) / 256, 256, 0, stream>>>(coords, owner, m0, N);
    scatter_write_kernel<<<(N + 255) / 256, 256, 0, stream>>>(feats, coords, owner, grid0, N);

    occupancy_kernel<3, 3, 2, 1, 1><<<(21 * 128 * 128 + 255) / 256, 256, 0, stream>>>(m0, m1, 41, 21);
    occupancy_kernel<3, 3, 2, 0, 1><<<(10 * 128 * 128 + 255) / 256, 256, 0, stream>>>(m1, m2, 21, 10);
    occupancy_kernel<3, 1, 2, 0, 0><<<(4 * 128 * 128 + 255) / 256, 256, 0, stream>>>(m2, m3, 10, 4);

    dim3 blk(256);
    // L0: 16->32, D 41->41
    conv_bnrelu_kernel<16, 32, 3, 3, 1, 1, 1><<<dim3(4, 128, 41), blk, 0, stream>>>(
        grid0, W_[0], S_[0], B_[0], m0, buf0, 41);
    // L1: 32->32, D 41 (overwrites grid0 region — grid no longer needed)
    conv_bnrelu_kernel<32, 32, 3, 3, 1, 1, 1><<<dim3(4, 128, 41), blk, 0, stream>>>(
        buf0, W_[1], S_[1], B_[1], m0, buf1, 41);
    // L2: 32->64, D 41->21 (stride 2, pad 1)
    conv_bnrelu_kernel<32, 64, 3, 3, 2, 1, 1><<<dim3(4, 128, 21), blk, 0, stream>>>(
        buf1, W_[2], S_[2], B_[2], m1, buf0, 41);
    // L3-5: 64->64, D 21
    conv_bnrelu_kernel<64, 64, 3, 3, 1, 1, 1><<<dim3(4, 128, 21), blk, 0, stream>>>(
        buf0, W_[3], S_[3], B_[3], m1, buf1, 21);
    conv_bnrelu_kernel<64, 64, 3, 3, 1, 1, 1><<<dim3(4, 128, 21), blk, 0, stream>>>(
        buf1, W_[4], S_[4], B_[4], m1, buf0, 21);
    conv_bnrelu_kernel<64, 64, 3, 3, 1, 1, 1><<<dim3(4, 128, 21), blk, 0, stream>>>(
        buf0, W_[5], S_[5], B_[5], m1, buf1, 21);
    // L6: 64->64, D 21->10 (stride 2, pad (0,1,1))
    conv_bnrelu_kernel<64, 64, 3, 3, 2, 0, 1><<<dim3(4, 128, 10), blk, 0, stream>>>(
        buf1, W_[6], S_[6], B_[6], m2, buf0, 21);
    // L7-9: 64->64, D 10
    conv_bnrelu_kernel<64, 64, 3, 3, 1, 1, 1><<<dim3(4, 128, 10), blk, 0, stream>>>(
        buf0, W_[7], S_[7], B_[7], m2, buf1, 10);
    conv_bnrelu_kernel<64, 64, 3, 3, 1, 1, 1><<<dim3(4, 128, 10), blk, 0, stream>>>(
        buf1, W_[8], S_[8], B_[8], m2, buf0, 10);
    conv_bnrelu_kernel<64, 64, 3, 3, 1, 1, 1><<<dim3(4, 128, 10), blk, 0, stream>>>(
        buf0, W_[9], S_[9], B_[9], m2, buf1, 10);
    // L10: 64->64, kernel (3,1,1), D 10->4, no pad — write straight to d_out
    conv_bnrelu_kernel<64, 64, 3, 1, 2, 0, 0><<<dim3(4, 128, 4), blk, 0, stream>>>(
        buf1, W_[10], S_[10], B_[10], m3, (float*)d_out, 10);
}

// Round 10
// 1196.915 us; speedup vs baseline: 5.8889x; 5.8889x over previous
//
#include <hip/hip_runtime.h>
#include <hip/hip_bf16.h>
#include <stdint.h>

// ---------------------------------------------------------------------------
// SpMiddle conv stack — fp16 MFMA implicit-GEMM version.
// Activations fp16 NDHWC between layers; fp32 MFMA accumulation; fp32 output.
// Weights pre-transposed on device to [kd][kh][kw][co][ci] fp16.
// ---------------------------------------------------------------------------

typedef _Float16 h8 __attribute__((ext_vector_type(8)));
typedef float f4 __attribute__((ext_vector_type(4)));

#define HCONST 128
#define WCONST 128

// ---- scatter: last-write-wins via owner = atomicMax(point index) ----------
__global__ void scatter_owner_kernel(const int* __restrict__ coords,
                                     int* __restrict__ owner,
                                     unsigned char* __restrict__ mask0, int N) {
    int n = blockIdx.x * blockDim.x + threadIdx.x;
    if (n >= N) return;
    int z = coords[n * 4 + 1];
    int y = coords[n * 4 + 2];
    int x = coords[n * 4 + 3];
    int pos = (z * HCONST + y) * WCONST + x;
    atomicMax(&owner[pos], n);
    mask0[pos] = 1;
}

// grid has 32 channels (ci 16..31 stay zero from memset); fp16
__global__ void scatter_write_kernel(const float* __restrict__ feats,
                                     const int* __restrict__ coords,
                                     const int* __restrict__ owner,
                                     _Float16* __restrict__ grid, int N) {
    int n = blockIdx.x * blockDim.x + threadIdx.x;
    if (n >= N) return;
    int z = coords[n * 4 + 1];
    int y = coords[n * 4 + 2];
    int x = coords[n * 4 + 3];
    int pos = (z * HCONST + y) * WCONST + x;
    if (owner[pos] != n) return;  // last write wins
    _Float16* d = grid + (size_t)pos * 32;
#pragma unroll
    for (int c = 0; c < 16; ++c) d[c] = (_Float16)feats[(size_t)n * 16 + c];
}

// ---- occupancy mask: OR over conv window -----------------------------------
template <int KD, int KHW, int SD, int PD, int PHW>
__global__ void occupancy_kernel(const unsigned char* __restrict__ min_,
                                 unsigned char* __restrict__ mout,
                                 int Din, int Dout) {
    int idx = blockIdx.x * blockDim.x + threadIdx.x;
    int total = Dout * HCONST * WCONST;
    if (idx >= total) return;
    int ow = idx % WCONST;
    int oh = (idx / WCONST) % HCONST;
    int od = idx / (WCONST * HCONST);
    unsigned char r = 0;
    for (int kd = 0; kd < KD; ++kd) {
        int d = od * SD - PD + kd;
        if (d < 0 || d >= Din) continue;
        for (int kh = 0; kh < KHW; ++kh) {
            int h = oh - PHW + kh;
            if ((unsigned)h >= (unsigned)HCONST) continue;
            for (int kw = 0; kw < KHW; ++kw) {
                int w = ow - PHW + kw;
                if ((unsigned)w >= (unsigned)WCONST) continue;
                r |= min_[(d * HCONST + h) * WCONST + w];
            }
        }
    }
    mout[idx] = r ? 1 : 0;
}

// ---- weight prep: fp32 [k][ci][co] -> fp16 [k][co][ciP] (ci-padded) --------
__global__ void prep_w_kernel(const float* __restrict__ src, _Float16* __restrict__ dst,
                              int K3, int CIN, int CINP, int COUT) {
    int idx = blockIdx.x * blockDim.x + threadIdx.x;
    int total = K3 * COUT * CINP;
    if (idx >= total) return;
    int k = idx / (COUT * CINP);
    int r = idx % (COUT * CINP);
    int co = r / CINP, ci = r % CINP;
    float v = (ci < CIN) ? src[((size_t)k * CIN + ci) * COUT + co] : 0.f;
    dst[idx] = (_Float16)v;
}

// ---- conv + BN + ReLU + mask, fp16 MFMA implicit GEMM ----------------------
// Block = one (od, oh): M = 128 w-positions, N = COUT. 4 waves in 2(M)x2(N).
// Per wave: M=64 (4 m-frags of 16) x N=COUT/2 (NFRAG n-frags of 16).
// A (activations) from LDS-staged input row; B (weights) from global
// [kd][kh][kw][co][ci] fp16 — one dwordx4 per fragment, register-resident
// per (kd,kh). MFMA 16x16x32 f16, fp32 accumulate.
template <int CIN, int COUT, int KD, int KHW, int SD, int PD, int PHW, bool OUT_F32>
__global__ __launch_bounds__(256) void conv_mfma_kernel(
    const _Float16* __restrict__ X, const _Float16* __restrict__ Wt,
    const float* __restrict__ scale, const float* __restrict__ bias,
    const unsigned char* __restrict__ mask, void* __restrict__ outv,
    int Din) {
    constexpr int KW = KHW, KH = KHW;
    constexpr int KS = CIN / 32;            // 32-wide k-slices per kw
    constexpr int NWAVE = COUT / 2;         // co-range per wave
    constexpr int NFRAG = NWAVE / 16;
    constexpr int PWOFF = (KHW == 3) ? 1 : 0;
    constexpr int WIN = 128 + 2 * PWOFF;    // staged w extent
    constexpr int STRIDE = CIN * 2 + 16;    // LDS row stride (bytes), breaks banks
    constexpr int CPR = CIN / 8;            // 16B chunks per row
    constexpr int CHUNKS = WIN * CPR;

    __shared__ char lds[WIN * STRIDE];

    const int tid = threadIdx.x;
    const int lane = tid & 63, wave = tid >> 6;
    const int wm = wave & 1, wn = wave >> 1;
    const int lm = lane & 15, lq = lane >> 4;
    const int oh = blockIdx.x, od = blockIdx.y;

    f4 acc[4][NFRAG];
#pragma unroll
    for (int mt = 0; mt < 4; ++mt)
#pragma unroll
        for (int nf = 0; nf < NFRAG; ++nf) acc[mt][nf] = (f4){0.f, 0.f, 0.f, 0.f};

    for (int kd = 0; kd < KD; ++kd) {
        int din = od * SD - PD + kd;
        if (din < 0 || din >= Din) continue;          // block-uniform
#pragma unroll
        for (int kh = 0; kh < KH; ++kh) {
            int hin = oh - PHW + kh;
            if ((unsigned)hin >= 128u) continue;      // block-uniform
            __syncthreads();                          // protect prev LDS reads
            const _Float16* src = X + (((size_t)din * 128 + hin) * 128) * CIN;
#pragma unroll
            for (int it = 0; it < (CHUNKS + 255) / 256; ++it) {
                int c = tid + it * 256;
                if (c < CHUNKS) {
                    int lw = c / CPR, cq = c % CPR;
                    int w = lw - PWOFF;
                    uint4 v = {0u, 0u, 0u, 0u};
                    if ((unsigned)w < 128u)
                        v = *(const uint4*)(src + (size_t)w * CIN + cq * 8);
                    *(uint4*)(lds + lw * STRIDE + cq * 16) = v;
                }
            }
            // B fragments for this (kd,kh): [kw][ks][nf], register-resident
            h8 Bf[KW][KS][NFRAG];
            const _Float16* wbase = Wt + (((size_t)kd * KH + kh) * KW) * COUT * CIN;
#pragma unroll
            for (int kw = 0; kw < KW; ++kw)
#pragma unroll
                for (int ks = 0; ks < KS; ++ks)
#pragma unroll
                    for (int nf = 0; nf < NFRAG; ++nf) {
                        int co = wn * NWAVE + nf * 16 + lm;
                        Bf[kw][ks][nf] =
                            *(const h8*)(wbase + ((size_t)kw * COUT + co) * CIN + ks * 32 + lq * 8);
                    }
            __syncthreads();
#pragma unroll
            for (int kw = 0; kw < KW; ++kw)
#pragma unroll
                for (int ks = 0; ks < KS; ++ks) {
                    h8 Af[4];
#pragma unroll
                    for (int mt = 0; mt < 4; ++mt) {
                        int row = wm * 64 + mt * 16 + lm + kw;  // lw = w_out + kw (PWOFF folds in)
                        Af[mt] = *(const h8*)(lds + row * STRIDE + ks * 64 + lq * 16);
                    }
#pragma unroll
                    for (int mt = 0; mt < 4; ++mt)
#pragma unroll
                        for (int nf = 0; nf < NFRAG; ++nf)
                            acc[mt][nf] = __builtin_amdgcn_mfma_f32_16x16x32_f16(
                                Af[mt], Bf[kw][ks][nf], acc[mt][nf], 0, 0, 0);
                }
        }
    }

    // epilogue: y = max(acc*s + b, 0) * mask; C layout col=lane&15(n), row=lq*4+r(m)
    const unsigned char* mrow = mask + ((size_t)od * 128 + oh) * 128;
    size_t obase = (((size_t)od * 128 + oh) * 128) * COUT;
#pragma unroll
    for (int nf = 0; nf < NFRAG; ++nf) {
        int co = wn * NWAVE + nf * 16 + lm;
        float s = scale[co];
        float b = bias[co];
#pragma unroll
        for (int mt = 0; mt < 4; ++mt) {
            int w0 = wm * 64 + mt * 16 + lq * 4;
#pragma unroll
            for (int r = 0; r < 4; ++r) {
                float y = fmaxf(acc[mt][nf][r] * s + b, 0.f);
                y = mrow[w0 + r] ? y : 0.f;
                if (OUT_F32)
                    ((float*)outv)[obase + (size_t)(w0 + r) * COUT + co] = y;
                else
                    ((_Float16*)outv)[obase + (size_t)(w0 + r) * COUT + co] = (_Float16)y;
            }
        }
    }
}

// ---------------------------------------------------------------------------
extern "C" void kernel_launch(void* const* d_in, const int* in_sizes, int n_in,
                              void* d_out, int out_size, void* d_ws, size_t ws_size,
                              hipStream_t stream) {
    const float* feats  = (const float*)d_in[0];
    const int*   coords = (const int*)d_in[1];
    const float* W_[11]; const float* S_[11]; const float* B_[11];
    for (int i = 0; i < 11; ++i) {
        W_[i] = (const float*)d_in[2 + 3 * i];
        S_[i] = (const float*)d_in[3 + 3 * i];
        B_[i] = (const float*)d_in[4 + 3 * i];
    }
    const int N = in_sizes[0] / 16;

    char* ws = (char*)d_ws;
    size_t off = 0;
    auto alloc = [&](size_t bytes) {
        void* p = ws + off;
        off = (off + bytes + 255) & ~(size_t)255;
        return p;
    };
    // fp16 ping-pong activation buffers (max layer: 344064*64 halves = 44 MB)
    const size_t BUF_BYTES = (size_t)22020096 * 2;
    _Float16* buf0 = (_Float16*)alloc(BUF_BYTES);
    _Float16* buf1 = (_Float16*)alloc(BUF_BYTES);
    unsigned char* m0 = (unsigned char*)alloc(671744);
    unsigned char* m1 = (unsigned char*)alloc(344064);
    unsigned char* m2 = (unsigned char*)alloc(163840);
    unsigned char* m3 = (unsigned char*)alloc(65536);
    int* owner = (int*)alloc((size_t)671744 * 4);
    // transposed fp16 weights
    static const int WT_SZ[11] = {27*32*32, 27*32*32, 27*64*32,
                                  27*64*64, 27*64*64, 27*64*64, 27*64*64,
                                  27*64*64, 27*64*64, 27*64*64, 3*64*64};
    _Float16* Wt[11];
    for (int i = 0; i < 11; ++i) Wt[i] = (_Float16*)alloc((size_t)WT_SZ[i] * 2);
    (void)ws_size; (void)n_in; (void)out_size;

    _Float16* grid0 = buf1;  // (41,128,128,32) fp16 aliased into buf1
    const size_t GRID_BYTES = (size_t)671744 * 32 * 2;

    hipMemsetAsync(grid0, 0, GRID_BYTES, stream);
    hipMemsetAsync(m0, 0, 671744, stream);
    hipMemsetAsync(owner, 0xFF, (size_t)671744 * 4, stream);

    scatter_owner_kernel<<<(N + 255) / 256, 256, 0, stream>>>(coords, owner, m0, N);
    scatter_write_kernel<<<(N + 255) / 256, 256, 0, stream>>>(feats, coords, owner, grid0, N);

    occupancy_kernel<3, 3, 2, 1, 1><<<(21 * 128 * 128 + 255) / 256, 256, 0, stream>>>(m0, m1, 41, 21);
    occupancy_kernel<3, 3, 2, 0, 1><<<(10 * 128 * 128 + 255) / 256, 256, 0, stream>>>(m1, m2, 21, 10);
    occupancy_kernel<3, 1, 2, 0, 0><<<(4 * 128 * 128 + 255) / 256, 256, 0, stream>>>(m2, m3, 10, 4);

    // weight prep (w0 padded ci 16->32)
    {
        static const int K3[11]   = {27,27,27,27,27,27,27,27,27,27,3};
        static const int CI[11]   = {16,32,32,64,64,64,64,64,64,64,64};
        static const int CIP[11]  = {32,32,32,64,64,64,64,64,64,64,64};
        static const int CO[11]   = {32,32,64,64,64,64,64,64,64,64,64};
        for (int i = 0; i < 11; ++i) {
            int total = K3[i] * CO[i] * CIP[i];
            prep_w_kernel<<<(total + 255) / 256, 256, 0, stream>>>(W_[i], Wt[i], K3[i], CI[i], CIP[i], CO[i]);
        }
    }

    // conv stack (blockIdx.x = oh, blockIdx.y = od)
    conv_mfma_kernel<32, 32, 3, 3, 1, 1, 1, false><<<dim3(128, 41), 256, 0, stream>>>(
        grid0, Wt[0], S_[0], B_[0], m0, buf0, 41);
    conv_mfma_kernel<32, 32, 3, 3, 1, 1, 1, false><<<dim3(128, 41), 256, 0, stream>>>(
        buf0, Wt[1], S_[1], B_[1], m0, buf1, 41);
    conv_mfma_kernel<32, 64, 3, 3, 2, 1, 1, false><<<dim3(128, 21), 256, 0, stream>>>(
        buf1, Wt[2], S_[2], B_[2], m1, buf0, 41);
    conv_mfma_kernel<64, 64, 3, 3, 1, 1, 1, false><<<dim3(128, 21), 256, 0, stream>>>(
        buf0, Wt[3], S_[3], B_[3], m1, buf1, 21);
    conv_mfma_kernel<64, 64, 3, 3, 1, 1, 1, false><<<dim3(128, 21), 256, 0, stream>>>(
        buf1, Wt[4], S_[4], B_[4], m1, buf0, 21);
    conv_mfma_kernel<64, 64, 3, 3, 1, 1, 1, false><<<dim3(128, 21), 256, 0, stream>>>(
        buf0, Wt[5], S_[5], B_[5], m1, buf1, 21);
    conv_mfma_kernel<64, 64, 3, 3, 2, 0, 1, false><<<dim3(128, 10), 256, 0, stream>>>(
        buf1, Wt[6], S_[6], B_[6], m2, buf0, 21);
    conv_mfma_kernel<64, 64, 3, 3, 1, 1, 1, false><<<dim3(128, 10), 256, 0, stream>>>(
        buf0, Wt[7], S_[7], B_[7], m2, buf1, 10);
    conv_mfma_kernel<64, 64, 3, 3, 1, 1, 1, false><<<dim3(128, 10), 256, 0, stream>>>(
        buf1, Wt[8], S_[8], B_[8], m2, buf0, 10);
    conv_mfma_kernel<64, 64, 3, 3, 1, 1, 1, false><<<dim3(128, 10), 256, 0, stream>>>(
        buf0, Wt[9], S_[9], B_[9], m2, buf1, 10);
    conv_mfma_kernel<64, 64, 3, 1, 2, 0, 0, true><<<dim3(128, 4), 256, 0, stream>>>(
        buf1, Wt[10], S_[10], B_[10], m3, (float*)d_out, 10);
}

// Round 11
// 974.539 us; speedup vs baseline: 7.2327x; 1.2282x over previous
//
#include <hip/hip_runtime.h>
#include <hip/hip_bf16.h>
#include <stdint.h>

// ---------------------------------------------------------------------------
// SpMiddle conv stack — fp16 MFMA implicit-GEMM, v3.
// vs v2: (1) stage all KH rows per kd (3 barriers/block not 9, 3x MFMA/phase),
//        (2) XOR-swizzled LDS (kills 4x bank-conflict of the +16B pad),
//        (3) weights repacked [k][ks][lq][co][8] for coalesced B-frag loads.
// ---------------------------------------------------------------------------

typedef _Float16 h8 __attribute__((ext_vector_type(8)));
typedef float f4 __attribute__((ext_vector_type(4)));

#define HCONST 128
#define WCONST 128

// ---- scatter: last-write-wins via owner = atomicMax(point index) ----------
__global__ void scatter_owner_kernel(const int* __restrict__ coords,
                                     int* __restrict__ owner,
                                     unsigned char* __restrict__ mask0, int N) {
    int n = blockIdx.x * blockDim.x + threadIdx.x;
    if (n >= N) return;
    int z = coords[n * 4 + 1];
    int y = coords[n * 4 + 2];
    int x = coords[n * 4 + 3];
    int pos = (z * HCONST + y) * WCONST + x;
    atomicMax(&owner[pos], n);
    mask0[pos] = 1;
}

// grid has 32 channels (ci 16..31 stay zero from memset); fp16
__global__ void scatter_write_kernel(const float* __restrict__ feats,
                                     const int* __restrict__ coords,
                                     const int* __restrict__ owner,
                                     _Float16* __restrict__ grid, int N) {
    int n = blockIdx.x * blockDim.x + threadIdx.x;
    if (n >= N) return;
    int z = coords[n * 4 + 1];
    int y = coords[n * 4 + 2];
    int x = coords[n * 4 + 3];
    int pos = (z * HCONST + y) * WCONST + x;
    if (owner[pos] != n) return;  // last write wins
    _Float16* d = grid + (size_t)pos * 32;
#pragma unroll
    for (int c = 0; c < 16; ++c) d[c] = (_Float16)feats[(size_t)n * 16 + c];
}

// ---- occupancy mask: OR over conv window -----------------------------------
template <int KD, int KHW, int SD, int PD, int PHW>
__global__ void occupancy_kernel(const unsigned char* __restrict__ min_,
                                 unsigned char* __restrict__ mout,
                                 int Din, int Dout) {
    int idx = blockIdx.x * blockDim.x + threadIdx.x;
    int total = Dout * HCONST * WCONST;
    if (idx >= total) return;
    int ow = idx % WCONST;
    int oh = (idx / WCONST) % HCONST;
    int od = idx / (WCONST * HCONST);
    unsigned char r = 0;
    for (int kd = 0; kd < KD; ++kd) {
        int d = od * SD - PD + kd;
        if (d < 0 || d >= Din) continue;
        for (int kh = 0; kh < KHW; ++kh) {
            int h = oh - PHW + kh;
            if ((unsigned)h >= (unsigned)HCONST) continue;
            for (int kw = 0; kw < KHW; ++kw) {
                int w = ow - PHW + kw;
                if ((unsigned)w >= (unsigned)WCONST) continue;
                r |= min_[(d * HCONST + h) * WCONST + w];
            }
        }
    }
    mout[idx] = r ? 1 : 0;
}

// ---- weight prep: fp32 [k][ci][co] -> fp16 [k][ks][lq][co][8] --------------
// MFMA-native: lane (lm,lq) of a wave reads co=base+lm at offset lq*16B;
// a quarter-wave's 16 loads are 256B contiguous.
__global__ void prep_w_kernel(const float* __restrict__ src, _Float16* __restrict__ dst,
                              int K3, int CIN, int CINP, int COUT) {
    int idx = blockIdx.x * blockDim.x + threadIdx.x;
    int total = K3 * CINP * COUT;           // CINP = KSP*4*8
    if (idx >= total) return;
    int j  = idx & 7;
    int t  = idx >> 3;
    int co = t % COUT; t /= COUT;
    int lq = t & 3;    t >>= 2;
    int KSP = CINP / 32;
    int ks = t % KSP;
    int k  = t / KSP;
    int ci = ks * 32 + lq * 8 + j;
    float v = (ci < CIN) ? src[((size_t)k * CIN + ci) * COUT + co] : 0.f;
    dst[idx] = (_Float16)v;
}

// ---- conv + BN + ReLU + mask, fp16 MFMA implicit GEMM ----------------------
// Block = one (od, oh): M = 128 w-positions, N = COUT. 4 waves in 2(M)x2(N).
// Per kd: stage KH rows (zero-filled at boundaries) into XOR-swizzled LDS,
// one barrier pair, then KH*KW*KS MFMA phases off the staged data.
template <int CIN, int COUT, int KD, int KHW, int SD, int PD, int PHW, bool OUT_F32>
__global__ __launch_bounds__(256) void conv_mfma_kernel(
    const _Float16* __restrict__ X, const _Float16* __restrict__ Wt,
    const float* __restrict__ scale, const float* __restrict__ bias,
    const unsigned char* __restrict__ mask, void* __restrict__ outv,
    int Din) {
    constexpr int KW = KHW, KH = KHW;
    constexpr int KS = CIN / 32;            // 32-wide k-slices per kw
    constexpr int NWAVE = COUT / 2;         // co-range per wave
    constexpr int NFRAG = NWAVE / 16;
    constexpr int PWOFF = (KHW == 3) ? 1 : 0;
    constexpr int WIN = 128 + 2 * PWOFF;    // staged w extent per row
    constexpr int CINB = CIN * 2;           // row bytes (power of 2 -> swizzle)
    constexpr int CPR = CIN / 8;            // 16B chunks per row
    constexpr int CHUNKS = KH * WIN * CPR;  // chunks staged per kd
    constexpr int NIT = (CHUNKS + 255) / 256;

    __shared__ char lds[KH * WIN * CINB];

    const int tid = threadIdx.x;
    const int lane = tid & 63, wave = tid >> 6;
    const int wm = wave & 1, wn = wave >> 1;
    const int lm = lane & 15, lq = lane >> 4;
    const int oh = blockIdx.x, od = blockIdx.y;

    f4 acc[4][NFRAG];
#pragma unroll
    for (int mt = 0; mt < 4; ++mt)
#pragma unroll
        for (int nf = 0; nf < NFRAG; ++nf) acc[mt][nf] = (f4){0.f, 0.f, 0.f, 0.f};

    for (int kd = 0; kd < KD; ++kd) {
        int din = od * SD - PD + kd;
        if (din < 0 || din >= Din) continue;          // block-uniform
        __syncthreads();                              // protect prev LDS reads
        // ---- stage KH rows for this kd (zero-fill OOB rows/cols) ----
        const _Float16* sbase = X + (size_t)din * 128 * 128 * CIN;
#pragma unroll
        for (int it = 0; it < NIT; ++it) {
            int c = tid + it * 256;
            if (c < CHUNKS) {
                int r  = c / CPR;           // staged row index (kh*WIN + lw)
                int cq = c % CPR;
                int khr = r / WIN;
                int lw  = r % WIN;
                int hin = oh - PHW + khr;
                int w   = lw - PWOFF;
                uint4 v = {0u, 0u, 0u, 0u};
                if ((unsigned)hin < 128u && (unsigned)w < 128u)
                    v = *(const uint4*)(sbase + ((size_t)hin * 128 + w) * CIN + cq * 8);
                int byte = r * CINB + ((cq * 16) ^ ((r & (CPR - 1)) << 4));
                *(uint4*)(lds + byte) = v;
            }
        }
        __syncthreads();
        // ---- compute: KH x KW x KS MFMA phases ----
#pragma unroll
        for (int kh = 0; kh < KH; ++kh) {
            h8 Bf[KW][KS][NFRAG];
            const _Float16* wbase = Wt + (size_t)(kd * KH + kh) * KW * KS * 4 * COUT * 8;
#pragma unroll
            for (int kw = 0; kw < KW; ++kw)
#pragma unroll
                for (int ks = 0; ks < KS; ++ks)
#pragma unroll
                    for (int nf = 0; nf < NFRAG; ++nf) {
                        int co = wn * NWAVE + nf * 16 + lm;
                        Bf[kw][ks][nf] =
                            *(const h8*)(wbase + (((size_t)(kw * KS + ks) * 4 + lq) * COUT + co) * 8);
                    }
#pragma unroll
            for (int kw = 0; kw < KW; ++kw)
#pragma unroll
                for (int ks = 0; ks < KS; ++ks) {
                    h8 Af[4];
#pragma unroll
                    for (int mt = 0; mt < 4; ++mt) {
                        int lw = wm * 64 + mt * 16 + lm + kw;
                        int r = kh * WIN + lw;
                        int byte = r * CINB + ((ks * 64 + lq * 16) ^ ((r & (CPR - 1)) << 4));
                        Af[mt] = *(const h8*)(lds + byte);
                    }
#pragma unroll
                    for (int mt = 0; mt < 4; ++mt)
#pragma unroll
                        for (int nf = 0; nf < NFRAG; ++nf)
                            acc[mt][nf] = __builtin_amdgcn_mfma_f32_16x16x32_f16(
                                Af[mt], Bf[kw][ks][nf], acc[mt][nf], 0, 0, 0);
                }
        }
    }

    // epilogue: y = max(acc*s + b, 0) * mask; C layout col=lane&15(n), row=lq*4+r(m)
    const unsigned char* mrow = mask + ((size_t)od * 128 + oh) * 128;
    size_t obase = (((size_t)od * 128 + oh) * 128) * COUT;
#pragma unroll
    for (int nf = 0; nf < NFRAG; ++nf) {
        int co = wn * NWAVE + nf * 16 + lm;
        float s = scale[co];
        float b = bias[co];
#pragma unroll
        for (int mt = 0; mt < 4; ++mt) {
            int w0 = wm * 64 + mt * 16 + lq * 4;
#pragma unroll
            for (int r = 0; r < 4; ++r) {
                float y = fmaxf(acc[mt][nf][r] * s + b, 0.f);
                y = mrow[w0 + r] ? y : 0.f;
                if (OUT_F32)
                    ((float*)outv)[obase + (size_t)(w0 + r) * COUT + co] = y;
                else
                    ((_Float16*)outv)[obase + (size_t)(w0 + r) * COUT + co] = (_Float16)y;
            }
        }
    }
}

// ---------------------------------------------------------------------------
extern "C" void kernel_launch(void* const* d_in, const int* in_sizes, int n_in,
                              void* d_out, int out_size, void* d_ws, size_t ws_size,
                              hipStream_t stream) {
    const float* feats  = (const float*)d_in[0];
    const int*   coords = (const int*)d_in[1];
    const float* W_[11]; const float* S_[11]; const float* B_[11];
    for (int i = 0; i < 11; ++i) {
        W_[i] = (const float*)d_in[2 + 3 * i];
        S_[i] = (const float*)d_in[3 + 3 * i];
        B_[i] = (const float*)d_in[4 + 3 * i];
    }
    const int N = in_sizes[0] / 16;

    char* ws = (char*)d_ws;
    size_t off = 0;
    auto alloc = [&](size_t bytes) {
        void* p = ws + off;
        off = (off + bytes + 255) & ~(size_t)255;
        return p;
    };
    // fp16 ping-pong activation buffers (max layer: 344064*64 halves = 44 MB)
    const size_t BUF_BYTES = (size_t)22020096 * 2;
    _Float16* buf0 = (_Float16*)alloc(BUF_BYTES);
    _Float16* buf1 = (_Float16*)alloc(BUF_BYTES);
    unsigned char* m0 = (unsigned char*)alloc(671744);
    unsigned char* m1 = (unsigned char*)alloc(344064);
    unsigned char* m2 = (unsigned char*)alloc(163840);
    unsigned char* m3 = (unsigned char*)alloc(65536);
    int* owner = (int*)alloc((size_t)671744 * 4);
    // repacked fp16 weights (element counts: K3 * COUT * CINP)
    static const int WT_SZ[11] = {27*32*32, 27*32*32, 27*64*32,
                                  27*64*64, 27*64*64, 27*64*64, 27*64*64,
                                  27*64*64, 27*64*64, 27*64*64, 3*64*64};
    _Float16* Wt[11];
    for (int i = 0; i < 11; ++i) Wt[i] = (_Float16*)alloc((size_t)WT_SZ[i] * 2);
    (void)ws_size; (void)n_in; (void)out_size;

    _Float16* grid0 = buf1;  // (41,128,128,32) fp16 aliased into buf1
    const size_t GRID_BYTES = (size_t)671744 * 32 * 2;

    hipMemsetAsync(grid0, 0, GRID_BYTES, stream);
    hipMemsetAsync(m0, 0, 671744, stream);
    hipMemsetAsync(owner, 0xFF, (size_t)671744 * 4, stream);

    scatter_owner_kernel<<<(N + 255) / 256, 256, 0, stream>>>(coords, owner, m0, N);
    scatter_write_kernel<<<(N + 255) / 256, 256, 0, stream>>>(feats, coords, owner, grid0, N);

    occupancy_kernel<3, 3, 2, 1, 1><<<(21 * 128 * 128 + 255) / 256, 256, 0, stream>>>(m0, m1, 41, 21);
    occupancy_kernel<3, 3, 2, 0, 1><<<(10 * 128 * 128 + 255) / 256, 256, 0, stream>>>(m1, m2, 21, 10);
    occupancy_kernel<3, 1, 2, 0, 0><<<(4 * 128 * 128 + 255) / 256, 256, 0, stream>>>(m2, m3, 10, 4);

    // weight prep (w0 padded ci 16->32); layout [k][ks][lq][co][8]
    {
        static const int K3[11]   = {27,27,27,27,27,27,27,27,27,27,3};
        static const int CI[11]   = {16,32,32,64,64,64,64,64,64,64,64};
        static const int CIP[11]  = {32,32,32,64,64,64,64,64,64,64,64};
        static const int CO[11]   = {32,32,64,64,64,64,64,64,64,64,64};
        for (int i = 0; i < 11; ++i) {
            int total = K3[i] * CO[i] * CIP[i];
            prep_w_kernel<<<(total + 255) / 256, 256, 0, stream>>>(W_[i], Wt[i], K3[i], CI[i], CIP[i], CO[i]);
        }
    }

    // conv stack (blockIdx.x = oh, blockIdx.y = od)
    conv_mfma_kernel<32, 32, 3, 3, 1, 1, 1, false><<<dim3(128, 41), 256, 0, stream>>>(
        grid0, Wt[0], S_[0], B_[0], m0, buf0, 41);
    conv_mfma_kernel<32, 32, 3, 3, 1, 1, 1, false><<<dim3(128, 41), 256, 0, stream>>>(
        buf0, Wt[1], S_[1], B_[1], m0, buf1, 41);
    conv_mfma_kernel<32, 64, 3, 3, 2, 1, 1, false><<<dim3(128, 21), 256, 0, stream>>>(
        buf1, Wt[2], S_[2], B_[2], m1, buf0, 41);
    conv_mfma_kernel<64, 64, 3, 3, 1, 1, 1, false><<<dim3(128, 21), 256, 0, stream>>>(
        buf0, Wt[3], S_[3], B_[3], m1, buf1, 21);
    conv_mfma_kernel<64, 64, 3, 3, 1, 1, 1, false><<<dim3(128, 21), 256, 0, stream>>>(
        buf1, Wt[4], S_[4], B_[4], m1, buf0, 21);
    conv_mfma_kernel<64, 64, 3, 3, 1, 1, 1, false><<<dim3(128, 21), 256, 0, stream>>>(
        buf0, Wt[5], S_[5], B_[5], m1, buf1, 21);
    conv_mfma_kernel<64, 64, 3, 3, 2, 0, 1, false><<<dim3(128, 10), 256, 0, stream>>>(
        buf1, Wt[6], S_[6], B_[6], m2, buf0, 21);
    conv_mfma_kernel<64, 64, 3, 3, 1, 1, 1, false><<<dim3(128, 10), 256, 0, stream>>>(
        buf0, Wt[7], S_[7], B_[7], m2, buf1, 10);
    conv_mfma_kernel<64, 64, 3, 3, 1, 1, 1, false><<<dim3(128, 10), 256, 0, stream>>>(
        buf1, Wt[8], S_[8], B_[8], m2, buf0, 10);
    conv_mfma_kernel<64, 64, 3, 3, 1, 1, 1, false><<<dim3(128, 10), 256, 0, stream>>>(
        buf0, Wt[9], S_[9], B_[9], m2, buf1, 10);
    conv_mfma_kernel<64, 64, 3, 1, 2, 0, 0, true><<<dim3(128, 4), 256, 0, stream>>>(
        buf1, Wt[10], S_[10], B_[10], m3, (float*)d_out, 10);
}

// Round 13
// 930.361 us; speedup vs baseline: 7.5761x; 1.0475x over previous
//
#include <hip/hip_runtime.h>
#include <hip/hip_bf16.h>
#include <stdint.h>

// ---------------------------------------------------------------------------
// SpMiddle conv stack — fp16 MFMA implicit-GEMM, v4.
// vs v3: w-dim split into two 64-wide tiles per block -> LDS 25KB (6 blk/CU),
// doubling co-resident blocks to hide stage/barrier latency (v3 measured
// occupancy 21%, 55% idle cycles). Swizzle + weight layout unchanged.
// ---------------------------------------------------------------------------

typedef _Float16 h8 __attribute__((ext_vector_type(8)));
typedef float f4 __attribute__((ext_vector_type(4)));

#define HCONST 128
#define WCONST 128

// ---- scatter: last-write-wins via owner = atomicMax(point index) ----------
__global__ void scatter_owner_kernel(const int* __restrict__ coords,
                                     int* __restrict__ owner,
                                     unsigned char* __restrict__ mask0, int N) {
    int n = blockIdx.x * blockDim.x + threadIdx.x;
    if (n >= N) return;
    int z = coords[n * 4 + 1];
    int y = coords[n * 4 + 2];
    int x = coords[n * 4 + 3];
    int pos = (z * HCONST + y) * WCONST + x;
    atomicMax(&owner[pos], n);
    mask0[pos] = 1;
}

// grid has 32 channels (ci 16..31 stay zero from memset); fp16
__global__ void scatter_write_kernel(const float* __restrict__ feats,
                                     const int* __restrict__ coords,
                                     const int* __restrict__ owner,
                                     _Float16* __restrict__ grid, int N) {
    int n = blockIdx.x * blockDim.x + threadIdx.x;
    if (n >= N) return;
    int z = coords[n * 4 + 1];
    int y = coords[n * 4 + 2];
    int x = coords[n * 4 + 3];
    int pos = (z * HCONST + y) * WCONST + x;
    if (owner[pos] != n) return;  // last write wins
    _Float16* d = grid + (size_t)pos * 32;
#pragma unroll
    for (int c = 0; c < 16; ++c) d[c] = (_Float16)feats[(size_t)n * 16 + c];
}

// ---- occupancy mask: OR over conv window -----------------------------------
template <int KD, int KHW, int SD, int PD, int PHW>
__global__ void occupancy_kernel(const unsigned char* __restrict__ min_,
                                 unsigned char* __restrict__ mout,
                                 int Din, int Dout) {
    int idx = blockIdx.x * blockDim.x + threadIdx.x;
    int total = Dout * HCONST * WCONST;
    if (idx >= total) return;
    int ow = idx % WCONST;
    int oh = (idx / WCONST) % HCONST;
    int od = idx / (WCONST * HCONST);
    unsigned char r = 0;
    for (int kd = 0; kd < KD; ++kd) {
        int d = od * SD - PD + kd;
        if (d < 0 || d >= Din) continue;
        for (int kh = 0; kh < KHW; ++kh) {
            int h = oh - PHW + kh;
            if ((unsigned)h >= (unsigned)HCONST) continue;
            for (int kw = 0; kw < KHW; ++kw) {
                int w = ow - PHW + kw;
                if ((unsigned)w >= (unsigned)WCONST) continue;
                r |= min_[(d * HCONST + h) * WCONST + w];
            }
        }
    }
    mout[idx] = r ? 1 : 0;
}

// ---- weight prep: fp32 [k][ci][co] -> fp16 [k][ks][lq][co][8] --------------
__global__ void prep_w_kernel(const float* __restrict__ src, _Float16* __restrict__ dst,
                              int K3, int CIN, int CINP, int COUT) {
    int idx = blockIdx.x * blockDim.x + threadIdx.x;
    int total = K3 * CINP * COUT;           // CINP = KSP*4*8
    if (idx >= total) return;
    int j  = idx & 7;
    int t  = idx >> 3;
    int co = t % COUT; t /= COUT;
    int lq = t & 3;    t >>= 2;
    int KSP = CINP / 32;
    int ks = t % KSP;
    int k  = t / KSP;
    int ci = ks * 32 + lq * 8 + j;
    float v = (ci < CIN) ? src[((size_t)k * CIN + ci) * COUT + co] : 0.f;
    dst[idx] = (_Float16)v;
}

// ---- conv + BN + ReLU + mask, fp16 MFMA implicit GEMM ----------------------
// Block = one (w-tile, oh, od): M = 64 w-positions, N = COUT.
// 4 waves in 2(M)x2(N): per wave M=32 (2 m-frags), N=COUT/2 (NFRAG n-frags).
// Per kd: stage KH rows x 66 w (zero-filled at boundaries) into XOR-swizzled
// LDS, one barrier pair, then KH*KW*KS MFMA phases off the staged data.
template <int CIN, int COUT, int KD, int KHW, int SD, int PD, int PHW, bool OUT_F32>
__global__ __launch_bounds__(256) void conv_mfma_kernel(
    const _Float16* __restrict__ X, const _Float16* __restrict__ Wt,
    const float* __restrict__ scale, const float* __restrict__ bias,
    const unsigned char* __restrict__ mask, void* __restrict__ outv,
    int Din) {
    constexpr int KW = KHW, KH = KHW;
    constexpr int KS = CIN / 32;            // 32-wide k-slices per kw
    constexpr int NWAVE = COUT / 2;         // co-range per wave
    constexpr int NFRAG = NWAVE / 16;
    constexpr int PWOFF = (KHW == 3) ? 1 : 0;
    constexpr int WINW = 64 + 2 * PWOFF;    // staged w extent per row (66|64)
    constexpr int CINB = CIN * 2;           // row bytes (power of 2 -> swizzle)
    constexpr int CPR = CIN / 8;            // 16B chunks per row
    constexpr int CHUNKS = KH * WINW * CPR; // chunks staged per kd
    constexpr int NIT = (CHUNKS + 255) / 256;

    __shared__ char lds[KH * WINW * CINB];

    const int tid = threadIdx.x;
    const int lane = tid & 63, wave = tid >> 6;
    const int wm = wave & 1, wn = wave >> 1;
    const int lm = lane & 15, lq = lane >> 4;
    const int wbase = blockIdx.x * 64;
    const int oh = blockIdx.y, od = blockIdx.z;

    f4 acc[2][NFRAG];
#pragma unroll
    for (int mt = 0; mt < 2; ++mt)
#pragma unroll
        for (int nf = 0; nf < NFRAG; ++nf) acc[mt][nf] = (f4){0.f, 0.f, 0.f, 0.f};

    for (int kd = 0; kd < KD; ++kd) {
        int din = od * SD - PD + kd;
        if (din < 0 || din >= Din) continue;          // block-uniform
        __syncthreads();                              // protect prev LDS reads
        // ---- stage KH rows for this kd (zero-fill OOB rows/cols) ----
        const _Float16* sbase = X + (size_t)din * 128 * 128 * CIN;
#pragma unroll
        for (int it = 0; it < NIT; ++it) {
            int c = tid + it * 256;
            if (c < CHUNKS) {
                int r  = c / CPR;           // staged row index (kh*WINW + lw)
                int cq = c % CPR;
                int khr = r / WINW;
                int lw  = r % WINW;
                int hin = oh - PHW + khr;
                int w   = wbase + lw - PWOFF;
                uint4 v = {0u, 0u, 0u, 0u};
                if ((unsigned)hin < 128u && (unsigned)w < 128u)
                    v = *(const uint4*)(sbase + ((size_t)hin * 128 + w) * CIN + cq * 8);
                int byte = r * CINB + ((cq * 16) ^ ((r & (CPR - 1)) << 4));
                *(uint4*)(lds + byte) = v;
            }
        }
        __syncthreads();
        // ---- compute: KH x KW x KS MFMA phases ----
#pragma unroll
        for (int kh = 0; kh < KH; ++kh) {
            h8 Bf[KW][KS][NFRAG];
            const _Float16* wbaseW = Wt + (size_t)(kd * KH + kh) * KW * KS * 4 * COUT * 8;
#pragma unroll
            for (int kw = 0; kw < KW; ++kw)
#pragma unroll
                for (int ks = 0; ks < KS; ++ks)
#pragma unroll
                    for (int nf = 0; nf < NFRAG; ++nf) {
                        int co = wn * NWAVE + nf * 16 + lm;
                        Bf[kw][ks][nf] =
                            *(const h8*)(wbaseW + (((size_t)(kw * KS + ks) * 4 + lq) * COUT + co) * 8);
                    }
#pragma unroll
            for (int kw = 0; kw < KW; ++kw)
#pragma unroll
                for (int ks = 0; ks < KS; ++ks) {
                    h8 Af[2];
#pragma unroll
                    for (int mt = 0; mt < 2; ++mt) {
                        int lw = wm * 32 + mt * 16 + lm + kw;
                        int r = kh * WINW + lw;
                        int byte = r * CINB + ((ks * 64 + lq * 16) ^ ((r & (CPR - 1)) << 4));
                        Af[mt] = *(const h8*)(lds + byte);
                    }
#pragma unroll
                    for (int mt = 0; mt < 2; ++mt)
#pragma unroll
                        for (int nf = 0; nf < NFRAG; ++nf)
                            acc[mt][nf] = __builtin_amdgcn_mfma_f32_16x16x32_f16(
                                Af[mt], Bf[kw][ks][nf], acc[mt][nf], 0, 0, 0);
                }
        }
    }

    // epilogue: y = max(acc*s + b, 0) * mask; C layout col=lane&15(n), row=lq*4+r(m)
    const unsigned char* mrow = mask + ((size_t)od * 128 + oh) * 128 + wbase;
    size_t obase = (((size_t)od * 128 + oh) * 128 + wbase) * COUT;
#pragma unroll
    for (int nf = 0; nf < NFRAG; ++nf) {
        int co = wn * NWAVE + nf * 16 + lm;
        float s = scale[co];
        float b = bias[co];
#pragma unroll
        for (int mt = 0; mt < 2; ++mt) {
            int w0 = wm * 32 + mt * 16 + lq * 4;
#pragma unroll
            for (int r = 0; r < 4; ++r) {
                float y = fmaxf(acc[mt][nf][r] * s + b, 0.f);
                y = mrow[w0 + r] ? y : 0.f;
                if (OUT_F32)
                    ((float*)outv)[obase + (size_t)(w0 + r) * COUT + co] = y;
                else
                    ((_Float16*)outv)[obase + (size_t)(w0 + r) * COUT + co] = (_Float16)y;
            }
        }
    }
}

// ---------------------------------------------------------------------------
extern "C" void kernel_launch(void* const* d_in, const int* in_sizes, int n_in,
                              void* d_out, int out_size, void* d_ws, size_t ws_size,
                              hipStream_t stream) {
    const float* feats  = (const float*)d_in[0];
    const int*   coords = (const int*)d_in[1];
    const float* W_[11]; const float* S_[11]; const float* B_[11];
    for (int i = 0; i < 11; ++i) {
        W_[i] = (const float*)d_in[2 + 3 * i];
        S_[i] = (const float*)d_in[3 + 3 * i];
        B_[i] = (const float*)d_in[4 + 3 * i];
    }
    const int N = in_sizes[0] / 16;

    char* ws = (char*)d_ws;
    size_t off = 0;
    auto alloc = [&](size_t bytes) {
        void* p = ws + off;
        off = (off + bytes + 255) & ~(size_t)255;
        return p;
    };
    // fp16 ping-pong activation buffers (max layer: 344064*64 halves = 44 MB)
    const size_t BUF_BYTES = (size_t)22020096 * 2;
    _Float16* buf0 = (_Float16*)alloc(BUF_BYTES);
    _Float16* buf1 = (_Float16*)alloc(BUF_BYTES);
    unsigned char* m0 = (unsigned char*)alloc(671744);
    unsigned char* m1 = (unsigned char*)alloc(344064);
    unsigned char* m2 = (unsigned char*)alloc(163840);
    unsigned char* m3 = (unsigned char*)alloc(65536);
    int* owner = (int*)alloc((size_t)671744 * 4);
    // repacked fp16 weights (element counts: K3 * COUT * CINP)
    static const int WT_SZ[11] = {27*32*32, 27*32*32, 27*64*32,
                                  27*64*64, 27*64*64, 27*64*64, 27*64*64,
                                  27*64*64, 27*64*64, 27*64*64, 3*64*64};
    _Float16* Wt[11];
    for (int i = 0; i < 11; ++i) Wt[i] = (_Float16*)alloc((size_t)WT_SZ[i] * 2);
    (void)ws_size; (void)n_in; (void)out_size;

    _Float16* grid0 = buf1;  // (41,128,128,32) fp16 aliased into buf1
    const size_t GRID_BYTES = (size_t)671744 * 32 * 2;

    hipMemsetAsync(grid0, 0, GRID_BYTES, stream);
    hipMemsetAsync(m0, 0, 671744, stream);
    hipMemsetAsync(owner, 0xFF, (size_t)671744 * 4, stream);

    scatter_owner_kernel<<<(N + 255) / 256, 256, 0, stream>>>(coords, owner, m0, N);
    scatter_write_kernel<<<(N + 255) / 256, 256, 0, stream>>>(feats, coords, owner, grid0, N);

    occupancy_kernel<3, 3, 2, 1, 1><<<(21 * 128 * 128 + 255) / 256, 256, 0, stream>>>(m0, m1, 41, 21);
    occupancy_kernel<3, 3, 2, 0, 1><<<(10 * 128 * 128 + 255) / 256, 256, 0, stream>>>(m1, m2, 21, 10);
    occupancy_kernel<3, 1, 2, 0, 0><<<(4 * 128 * 128 + 255) / 256, 256, 0, stream>>>(m2, m3, 10, 4);

    // weight prep (w0 padded ci 16->32); layout [k][ks][lq][co][8]
    {
        static const int K3[11]   = {27,27,27,27,27,27,27,27,27,27,3};
        static const int CI[11]   = {16,32,32,64,64,64,64,64,64,64,64};
        static const int CIP[11]  = {32,32,32,64,64,64,64,64,64,64,64};
        static const int CO[11]   = {32,32,64,64,64,64,64,64,64,64,64};
        for (int i = 0; i < 11; ++i) {
            int total = K3[i] * CO[i] * CIP[i];
            prep_w_kernel<<<(total + 255) / 256, 256, 0, stream>>>(W_[i], Wt[i], K3[i], CI[i], CIP[i], CO[i]);
        }
    }

    // conv stack (blockIdx = {w-tile, oh, od})
    conv_mfma_kernel<32, 32, 3, 3, 1, 1, 1, false><<<dim3(2, 128, 41), 256, 0, stream>>>(
        grid0, Wt[0], S_[0], B_[0], m0, buf0, 41);
    conv_mfma_kernel<32, 32, 3, 3, 1, 1, 1, false><<<dim3(2, 128, 41), 256, 0, stream>>>(
        buf0, Wt[1], S_[1], B_[1], m0, buf1, 41);
    conv_mfma_kernel<32, 64, 3, 3, 2, 1, 1, false><<<dim3(2, 128, 21), 256, 0, stream>>>(
        buf1, Wt[2], S_[2], B_[2], m1, buf0, 41);
    conv_mfma_kernel<64, 64, 3, 3, 1, 1, 1, false><<<dim3(2, 128, 21), 256, 0, stream>>>(
        buf0, Wt[3], S_[3], B_[3], m1, buf1, 21);
    conv_mfma_kernel<64, 64, 3, 3, 1, 1, 1, false><<<dim3(2, 128, 21), 256, 0, stream>>>(
        buf1, Wt[4], S_[4], B_[4], m1, buf0, 21);
    conv_mfma_kernel<64, 64, 3, 3, 1, 1, 1, false><<<dim3(2, 128, 21), 256, 0, stream>>>(
        buf0, Wt[5], S_[5], B_[5], m1, buf1, 21);
    conv_mfma_kernel<64, 64, 3, 3, 2, 0, 1, false><<<dim3(2, 128, 10), 256, 0, stream>>>(
        buf1, Wt[6], S_[6], B_[6], m2, buf0, 21);
    conv_mfma_kernel<64, 64, 3, 3, 1, 1, 1, false><<<dim3(2, 128, 10), 256, 0, stream>>>(
        buf0, Wt[7], S_[7], B_[7], m2, buf1, 10);
    conv_mfma_kernel<64, 64, 3, 3, 1, 1, 1, false><<<dim3(2, 128, 10), 256, 0, stream>>>(
        buf1, Wt[8], S_[8], B_[8], m2, buf0, 10);
    conv_mfma_kernel<64, 64, 3, 3, 1, 1, 1, false><<<dim3(2, 128, 10), 256, 0, stream>>>(
        buf0, Wt[9], S_[9], B_[9], m2, buf1, 10);
    conv_mfma_kernel<64, 64, 3, 1, 2, 0, 0, true><<<dim3(2, 128, 4), 256, 0, stream>>>(
        buf1, Wt[10], S_[10], B_[10], m3, (float*)d_out, 10);
}